// Round 12
// baseline (468.221 us; speedup 1.0000x reference)
//
#include <hip/hip_runtime.h>

#define B_DIM 4096
#define I_DIM 1024
#define H_DIM 2048
#define O_DIM 512

typedef unsigned short ushort_t;
typedef unsigned long long ull_t;
typedef __attribute__((ext_vector_type(4))) float f32x4;
typedef __attribute__((ext_vector_type(8))) short bf16x8;     // 8 bf16 bit-patterns (4 VGPRs)
typedef __attribute__((ext_vector_type(8))) unsigned short u16x8;
typedef __attribute__((ext_vector_type(4))) unsigned short u16x4;

// ---- bf16 helpers (RNE) ----
__device__ __forceinline__ unsigned short f2bf(float f) {
  union { float f; unsigned int u; } v; v.f = f;
  unsigned int u = v.u;
  u += 0x7fffu + ((u >> 16) & 1u);
  return (unsigned short)(u >> 16);
}
__device__ __forceinline__ float bf2f(unsigned short h) {
  union { unsigned int u; float f; } v; v.u = ((unsigned int)h) << 16;
  return v.f;
}

// ---- async global->LDS, 16B per lane. LDS dest must be wave-uniform base + lane*16. ----
__device__ __forceinline__ void gld16(const void* g, void* l) {
  __builtin_amdgcn_global_load_lds(
      (const __attribute__((address_space(1))) unsigned int*)((ull_t)g),
      (__attribute__((address_space(3))) unsigned int*)((unsigned int)(ull_t)l),
      16, 0, 0);
}

// st_16x32 swizzle within a [rows][64] bf16 tile stored as [16-row][32-col] subtiles:
// byte off ^= ((off>>9)&1)<<5 inside each 1024B subtile (involution).
__device__ __forceinline__ int swz_off(int row, int col) {
  int off = ((((row >> 4) << 1) + (col >> 5)) << 10) + ((row & 15) << 6) + ((col & 31) << 1);
  off ^= ((row >> 3) & 1) << 5;
  return off;
}

// =====================================================================
// Parameterized tile GEMM: BM=WM*MR*16, BN=WN*NR*16, BK=64, WM*WN waves,
// double-buffered swizzled LDS, counted vmcnt, PIPELINED phases:
//   entry: vmcnt+barrier; read a_lo,b_lo; lgkm0
//   p0: issue b_hi+a_hi reads (fly under MFMA); MFMA q(0,0)
//   p1: lgkm0; MFMA q(0,1)
//   barrier  (every wave passed p1's lgkm0 -> ALL buf-b reads drained)
//   p2: stageB(kt+2); MFMA q(1,1)
//   p3: stageA(kt+2); MFMA q(1,0)     (split stage issue, R7-measured)
// 2 barriers/K-tile. Direct global-store epilogue (R9 LDS-bounce was worse).
// C[M,N] = act(A[M,K] @ Bt[N,K]^T + bias)
// =====================================================================
template <bool RELU, int WM, int WN, int MR, int NR>
__device__ __forceinline__ void gemm_core(
    const ushort_t* __restrict__ A,    // [M][K] bf16 bits, row-major
    const ushort_t* __restrict__ Bt,   // [N][K] bf16 bits, row-major
    const float*    __restrict__ bias, // [N]
    ushort_t*       __restrict__ C,    // [M][N] bf16 bits
    int N, int K, int bm0, int bn0)
{
  constexpr int BM = WM * MR * 16;
  constexpr int BN = WN * NR * 16;
  constexpr int NTH = WM * WN * 64;
  constexpr int MH = MR / 2, NH = NR / 2;
  constexpr int ABYTES = BM * 128;     // BM x 64 x 2B
  constexpr int BBYTES = BN * 128;
  constexpr int CA = ABYTES / (NTH * 16);   // 16B staging chunks / thread / K-tile
  constexpr int CB = BBYTES / (NTH * 16);
  constexpr int VM = CA + CB;          // per-thread loads per K-tile

  __shared__ __align__(16) char lds[2 * (ABYTES + BBYTES)];

  const int tid  = threadIdx.x;
  const int lane = tid & 63;
  const int wave = tid >> 6;
  const int wm = wave / WN, wn = wave % WN;
  const int r16 = lane & 15, kq = lane >> 4;

  // ---- staging maps: linear LDS dest + inverse-swizzled global source ----
  int loffA[CA]; ull_t goffA[CA];
  int loffB[CB]; ull_t goffB[CB];
#pragma unroll
  for (int r = 0; r < CA; ++r) {
    const int L = (r * NTH + tid) * 16;
    const int P = L ^ (((L >> 9) & 1) << 5);
    const int s = P >> 10;
    const int row = ((s >> 1) << 4) | ((P >> 6) & 15);
    const int col = ((s & 1) << 5) | (((P >> 4) & 3) << 3);
    loffA[r] = L;
    goffA[r] = (ull_t)(bm0 + row) * K + col;
  }
#pragma unroll
  for (int r = 0; r < CB; ++r) {
    const int L = (r * NTH + tid) * 16;
    const int P = L ^ (((L >> 9) & 1) << 5);
    const int s = P >> 10;
    const int row = ((s >> 1) << 4) | ((P >> 6) & 15);
    const int col = ((s & 1) << 5) | (((P >> 4) & 3) << 3);
    loffB[r] = L;
    goffB[r] = (ull_t)(bn0 + row) * K + col;
  }
  const int NT = K >> 6;

  // ---- swizzled read offsets, constant across K-tiles ----
  int offA[MR][2], offB[NR][2];
#pragma unroll
  for (int m = 0; m < MR; ++m)
#pragma unroll
    for (int ks = 0; ks < 2; ++ks)
      offA[m][ks] = swz_off(wm * MR * 16 + m * 16 + r16, ks * 32 + kq * 8);
#pragma unroll
  for (int n = 0; n < NR; ++n)
#pragma unroll
    for (int ks = 0; ks < 2; ++ks)
      offB[n][ks] = swz_off(wn * NR * 16 + n * 16 + r16, ks * 32 + kq * 8);

  f32x4 acc[MR][NR] = {};

  auto stageA = [&](int b, int kt) {
    char* base = lds + b * (ABYTES + BBYTES);
    const int k0 = kt << 6;
#pragma unroll
    for (int r = 0; r < CA; ++r) gld16(A + goffA[r] + k0, base + loffA[r]);
  };
  auto stageB = [&](int b, int kt) {
    char* base = lds + b * (ABYTES + BBYTES) + ABYTES;
    const int k0 = kt << 6;
#pragma unroll
    for (int r = 0; r < CB; ++r) gld16(Bt + goffB[r] + k0, base + loffB[r]);
  };

  stageA(0, 0); stageB(0, 0);
  stageA(1, 1); stageB(1, 1);   // NT >= 2 always here

  for (int kt = 0; kt < NT; ++kt) {
    const int b = kt & 1;
    const bool pre = (kt + 2 < NT);
    if (kt < NT - 1) {
      if constexpr (VM == 8)      asm volatile("s_waitcnt vmcnt(8)" ::: "memory");
      else if constexpr (VM == 4) asm volatile("s_waitcnt vmcnt(4)" ::: "memory");
      else                        asm volatile("s_waitcnt vmcnt(0)" ::: "memory");
    } else {
      asm volatile("s_waitcnt vmcnt(0)" ::: "memory");
    }
    __builtin_amdgcn_s_barrier();   // entry: all waves' kt loads landed & visible

    const char* tA = lds + b * (ABYTES + BBYTES);
    const char* tB = tA + ABYTES;

    bf16x8 a_lo[MH][2], a_hi[MH][2], b_lo[NH][2], b_hi[NH][2];

    // ---- phase-0 fragment reads ----
#pragma unroll
    for (int m = 0; m < MH; ++m) {
      a_lo[m][0] = *(const bf16x8*)(tA + offA[m][0]);
      a_lo[m][1] = *(const bf16x8*)(tA + offA[m][1]);
    }
#pragma unroll
    for (int n = 0; n < NH; ++n) {
      b_lo[n][0] = *(const bf16x8*)(tB + offB[n][0]);
      b_lo[n][1] = *(const bf16x8*)(tB + offB[n][1]);
    }
    asm volatile("s_waitcnt lgkmcnt(0)" ::: "memory");
    __builtin_amdgcn_sched_barrier(0);

    // ---- p0: issue b_hi + a_hi reads (overlap with MFMA), MFMA q(0,0) ----
#pragma unroll
    for (int n = 0; n < NH; ++n) {
      b_hi[n][0] = *(const bf16x8*)(tB + offB[n + NH][0]);
      b_hi[n][1] = *(const bf16x8*)(tB + offB[n + NH][1]);
    }
#pragma unroll
    for (int m = 0; m < MH; ++m) {
      a_hi[m][0] = *(const bf16x8*)(tA + offA[m + MH][0]);
      a_hi[m][1] = *(const bf16x8*)(tA + offA[m + MH][1]);
    }
    __builtin_amdgcn_sched_barrier(0);
    __builtin_amdgcn_s_setprio(1);
#pragma unroll
    for (int m = 0; m < MH; ++m)
#pragma unroll
      for (int n = 0; n < NH; ++n)
#pragma unroll
        for (int ks = 0; ks < 2; ++ks)
          acc[m][n] = __builtin_amdgcn_mfma_f32_16x16x32_bf16(a_lo[m][ks], b_lo[n][ks], acc[m][n], 0, 0, 0);
    __builtin_amdgcn_s_setprio(0);

    // ---- p1: wait reads, MFMA q(0,1) ----
    asm volatile("s_waitcnt lgkmcnt(0)" ::: "memory");
    __builtin_amdgcn_sched_barrier(0);
    __builtin_amdgcn_s_setprio(1);
#pragma unroll
    for (int m = 0; m < MH; ++m)
#pragma unroll
      for (int n = 0; n < NH; ++n)
#pragma unroll
        for (int ks = 0; ks < 2; ++ks)
          acc[m][n + NH] = __builtin_amdgcn_mfma_f32_16x16x32_bf16(a_lo[m][ks], b_hi[n][ks], acc[m][n + NH], 0, 0, 0);
    __builtin_amdgcn_s_setprio(0);
    asm volatile("" ::: "memory");
    __builtin_amdgcn_s_barrier();   // every wave passed p1's lgkm0 -> all buf-b reads drained

    // ---- p2: stage B(kt+2), MFMA q(1,1) ----
    if (pre) stageB(b, kt + 2);
    __builtin_amdgcn_sched_barrier(0);
    __builtin_amdgcn_s_setprio(1);
#pragma unroll
    for (int m = 0; m < MH; ++m)
#pragma unroll
      for (int n = 0; n < NH; ++n)
#pragma unroll
        for (int ks = 0; ks < 2; ++ks)
          acc[m + MH][n + NH] = __builtin_amdgcn_mfma_f32_16x16x32_bf16(a_hi[m][ks], b_hi[n][ks], acc[m + MH][n + NH], 0, 0, 0);
    __builtin_amdgcn_s_setprio(0);

    // ---- p3: stage A(kt+2), MFMA q(1,0) ----
    if (pre) stageA(b, kt + 2);
    __builtin_amdgcn_sched_barrier(0);
    __builtin_amdgcn_s_setprio(1);
#pragma unroll
    for (int m = 0; m < MH; ++m)
#pragma unroll
      for (int n = 0; n < NH; ++n)
#pragma unroll
        for (int ks = 0; ks < 2; ++ks)
          acc[m + MH][n] = __builtin_amdgcn_mfma_f32_16x16x32_bf16(a_hi[m][ks], b_lo[n][ks], acc[m + MH][n], 0, 0, 0);
    __builtin_amdgcn_s_setprio(0);
  }

  // ---- epilogue: direct global stores (measured best) ----
  float bv[NR];
#pragma unroll
  for (int n = 0; n < NR; ++n) bv[n] = bias[bn0 + wn * NR * 16 + n * 16 + r16];
#pragma unroll
  for (int m = 0; m < MR; ++m) {
    const int row = bm0 + wm * MR * 16 + m * 16 + kq * 4;
#pragma unroll
    for (int n = 0; n < NR; ++n) {
      const int col = bn0 + wn * NR * 16 + n * 16 + r16;
#pragma unroll
      for (int j = 0; j < 4; ++j) {
        float v = acc[m][n][j] + bv[n];
        if (RELU) v = fmaxf(v, 0.f);
        C[(ull_t)(row + j) * N + col] = f2bf(v);
      }
    }
  }
}

// bijective XCD swizzle of the flattened grid (total % 8 == 0 for all our grids)
__device__ __forceinline__ void xcd_swz(int& bx, int& by, int& bz) {
  const int gx = gridDim.x, gy = gridDim.y;
  const int total = gx * gy * gridDim.z;
  const int flat = blockIdx.x + gx * (blockIdx.y + gy * blockIdx.z);
  const int q = total >> 3;
  const int s = (flat & 7) * q + (flat >> 3);
  bx = s % gx;
  const int rest = s / gx;
  by = rest % gy;
  bz = rest / gy;
}

// expert order: 0-3 = task1, 4-7 = task2, 8-11 = shared
__global__ __launch_bounds__(512, 2) void gemm1_256_kernel(
    const ushort_t* __restrict__ xb,   // [3][B][I] bf16 (slot 0=t1,1=t2,2=sh)
    const ushort_t* __restrict__ w1t,  // [cnt][H][I] bf16
    const float* __restrict__ b1_t1, const float* __restrict__ b1_t2, const float* __restrict__ b1_sh,
    ushort_t* __restrict__ hbuf,       // [cnt][B][H] bf16
    int ebase)
{
  int bx, by, bz; xcd_swz(bx, by, bz);
  const int eg = ebase + bz;
  const ushort_t* A  = xb + (ull_t)(eg >> 2) * B_DIM * I_DIM;
  const ushort_t* Bt = w1t + (ull_t)bz * H_DIM * I_DIM;
  const float* bias = (eg < 4 ? b1_t1 : eg < 8 ? b1_t2 : b1_sh) + (ull_t)(eg & 3) * H_DIM;
  ushort_t* C = hbuf + (ull_t)bz * B_DIM * H_DIM;
  gemm_core<true, 2, 4, 8, 4>(A, Bt, bias, C, H_DIM, I_DIM, by * 256, bx * 256);
}

// gemm2: 128x128 tile, 4 waves, 64KB LDS -> 2 blocks/CU; grid 4x32x12 = 1536 = 3 rounds
__global__ __launch_bounds__(256, 2) void gemm2_128_kernel(
    const ushort_t* __restrict__ hbuf, // [cnt][B][H] bf16
    const ushort_t* __restrict__ w2t,  // [cnt][O][H] bf16
    const float* __restrict__ b2_t1, const float* __restrict__ b2_t2, const float* __restrict__ b2_sh,
    ushort_t* __restrict__ eout,       // [12][B][O] bf16
    int ebase)
{
  int bx, by, bz; xcd_swz(bx, by, bz);
  const int eg = ebase + bz;
  const ushort_t* A  = hbuf + (ull_t)bz * B_DIM * H_DIM;
  const ushort_t* Bt = w2t + (ull_t)bz * O_DIM * H_DIM;
  const float* bias = (eg < 4 ? b2_t1 : eg < 8 ? b2_t2 : b2_sh) + (ull_t)(eg & 3) * O_DIM;
  ushort_t* C = eout + (ull_t)eg * B_DIM * O_DIM;
  gemm_core<false, 2, 2, 4, 4>(A, Bt, bias, C, O_DIM, H_DIM, by * 128, bx * 128);
}

// transpose-cast fp32 [R][C] -> bf16 [C][R]; 64x32 tiles, u16x8 (16B) writes
__global__ void tcast64_kernel(const float* __restrict__ s_t1, const float* __restrict__ s_t2,
                               const float* __restrict__ s_sh, ushort_t* __restrict__ dst,
                               int R, int C, int ebase)
{
  __shared__ float tile[64][33];
  const int eg = ebase + blockIdx.z;
  const float* src = (eg < 4 ? s_t1 : eg < 8 ? s_t2 : s_sh) + (ull_t)(eg & 3) * R * C;
  ushort_t* d = dst + (ull_t)blockIdx.z * R * C;
  const int tx = threadIdx.x, ty = threadIdx.y;   // 32 x 8
  const int r0 = blockIdx.y * 64, c0 = blockIdx.x * 32;
#pragma unroll
  for (int i = 0; i < 64; i += 8)
    tile[i + ty][tx] = src[(ull_t)(r0 + i + ty) * C + c0 + tx];
  __syncthreads();
  const int tid = ty * 32 + tx;
  const int c = tid >> 3, q = tid & 7;
  u16x8 rv;
#pragma unroll
  for (int k = 0; k < 8; ++k) rv[k] = f2bf(tile[q * 8 + k][c]);
  *(u16x8*)(d + (ull_t)(c0 + c) * R + r0 + q * 8) = rv;
}

// cast x fp32 -> bf16, 8 elems/thread
__global__ void cast_x_kernel(const float* __restrict__ xt1, const float* __restrict__ xt2,
                              const float* __restrict__ xsh, ushort_t* __restrict__ dst)
{
  const int slot = blockIdx.y;
  const float* src = slot == 0 ? xt1 : slot == 1 ? xt2 : xsh;
  const ull_t base = ((ull_t)blockIdx.x * 256 + threadIdx.x) * 8;
  const f32x4* s4 = (const f32x4*)(src + base);
  f32x4 a = s4[0], b = s4[1];
  u16x8 r;
  r[0] = f2bf(a[0]); r[1] = f2bf(a[1]); r[2] = f2bf(a[2]); r[3] = f2bf(a[3]);
  r[4] = f2bf(b[0]); r[5] = f2bf(b[1]); r[6] = f2bf(b[2]); r[7] = f2bf(b[3]);
  *(u16x8*)(dst + (ull_t)slot * B_DIM * I_DIM + base) = r;
}

// prep: transpose-cast gate weights [1024][n] fp32 -> [16][1024] bf16 (zero-padded cols)
__global__ void prep_gates_w_kernel(const float* __restrict__ wg_sh, const float* __restrict__ wg_t1,
                                    const float* __restrict__ wg_t2, ushort_t* __restrict__ wgtb)
{
  const int t = blockIdx.x;
  const float* src = t == 0 ? wg_sh : t == 1 ? wg_t1 : wg_t2;
  const int n = t == 0 ? 12 : 8;
  ushort_t* dst = wgtb + (ull_t)t * 16 * I_DIM;
  for (int i = threadIdx.x; i < 16 * (I_DIM / 8); i += blockDim.x) {
    const int c = i >> 7, j0 = (i & 127) * 8;
    u16x8 r;
#pragma unroll
    for (int k = 0; k < 8; ++k)
      r[k] = (c < n) ? f2bf(src[(ull_t)(j0 + k) * n + c]) : (ushort_t)0;
    *(u16x8*)(dst + (ull_t)c * I_DIM + j0) = r;
  }
}

// gates, LDS-free: each wave computes 16 rows x 16 gate-cols via direct-read
// MFMA (dual acc chains for ILP), then 16-lane-group softmax.
__global__ __launch_bounds__(256) void gates_direct_kernel(
    const ushort_t* __restrict__ xb, const ushort_t* __restrict__ wgtb,
    const float* __restrict__ bg_sh, const float* __restrict__ bg_t1, const float* __restrict__ bg_t2,
    float* __restrict__ gates)  // gs[B][12] | g1[B][8] | g2[B][8]
{
  const int task = blockIdx.y;
  const int slot = task == 0 ? 2 : task - 1;
  const int n = task == 0 ? 12 : 8;
  const float* bg = task == 0 ? bg_sh : task == 1 ? bg_t1 : bg_t2;
  float* out = task == 0 ? gates
             : task == 1 ? gates + (ull_t)B_DIM * 12
                         : gates + (ull_t)B_DIM * 20;

  const int lane = threadIdx.x & 63, wave = threadIdx.x >> 6;
  const int r16 = lane & 15, kq = lane >> 4;
  const int brow = blockIdx.x * 64 + wave * 16;

  const ushort_t* Arow = xb + (ull_t)slot * B_DIM * I_DIM + (ull_t)(brow + r16) * I_DIM + kq * 8;
  const ushort_t* Brow = wgtb + (ull_t)task * 16 * I_DIM + (ull_t)r16 * I_DIM + kq * 8;

  f32x4 acc0 = {}, acc1 = {};
#pragma unroll
  for (int k0 = 0; k0 < I_DIM; k0 += 64) {
    const bf16x8 a0 = *(const bf16x8*)(Arow + k0);
    const bf16x8 b0 = *(const bf16x8*)(Brow + k0);
    const bf16x8 a1 = *(const bf16x8*)(Arow + k0 + 32);
    const bf16x8 b1 = *(const bf16x8*)(Brow + k0 + 32);
    acc0 = __builtin_amdgcn_mfma_f32_16x16x32_bf16(a0, b0, acc0, 0, 0, 0);
    acc1 = __builtin_amdgcn_mfma_f32_16x16x32_bf16(a1, b1, acc1, 0, 0, 0);
  }

  const float bv = (r16 < n) ? bg[r16] : 0.f;
#pragma unroll
  for (int j = 0; j < 4; ++j) {
    float v = (r16 < n) ? (acc0[j] + acc1[j] + bv) : -1e30f;
    float mx = v;
#pragma unroll
    for (int d = 1; d < 16; d <<= 1) mx = fmaxf(mx, __shfl_xor(mx, d));
    const float e = __expf(v - mx);
    float s = e;
#pragma unroll
    for (int d = 1; d < 16; d <<= 1) s += __shfl_xor(s, d);
    const int row = brow + kq * 4 + j;
    if (r16 < n) out[(ull_t)row * n + r16] = e / s;
  }
}

// combine: out_sh = sum_j gs[j]*E[j]; out1 = g1 over {t1,sh}; out2 = g2 over {t2,sh}
__global__ __launch_bounds__(256) void combine_kernel(
    const ushort_t* __restrict__ eout, const float* __restrict__ gates, float* __restrict__ out)
{
  const ull_t idx8 = (ull_t)blockIdx.x * 256 + threadIdx.x;  // over B*O/8
  const int b  = (int)(idx8 >> 6);          // O/8 = 64 groups per row
  const int o8 = ((int)idx8 & 63) * 8;
  const float* gs = gates + (ull_t)b * 12;
  const float* g1 = gates + (ull_t)B_DIM * 12 + (ull_t)b * 8;
  const float* g2 = gates + (ull_t)B_DIM * 20 + (ull_t)b * 8;
  float osh[8] = {}, o1[8] = {}, o2[8] = {};
#pragma unroll
  for (int j = 0; j < 12; ++j) {
    const u16x8 ev = *(const u16x8*)(eout + ((ull_t)j * B_DIM + b) * O_DIM + o8);
    const float wsh = gs[j];
    const float w1 = (j < 4) ? g1[j] : (j >= 8 ? g1[j - 4] : 0.f);
    const float w2 = (j < 4) ? 0.f : g2[j - 4];
#pragma unroll
    for (int t = 0; t < 8; ++t) {
      const float e = bf2f(ev[t]);
      osh[t] += wsh * e; o1[t] += w1 * e; o2[t] += w2 * e;
    }
  }
  const ull_t nBO = (ull_t)B_DIM * O_DIM;
  const ull_t obase = (ull_t)b * O_DIM + o8;
#pragma unroll
  for (int h = 0; h < 2; ++h) {
    f32x4 v0 = {osh[h*4], osh[h*4+1], osh[h*4+2], osh[h*4+3]};
    f32x4 v1 = {o1[h*4], o1[h*4+1], o1[h*4+2], o1[h*4+3]};
    f32x4 v2 = {o2[h*4], o2[h*4+1], o2[h*4+2], o2[h*4+3]};
    *(f32x4*)(out + obase + h*4) = v0;
    *(f32x4*)(out + nBO + obase + h*4) = v1;
    *(f32x4*)(out + 2 * nBO + obase + h*4) = v2;
  }
}

extern "C" void kernel_launch(void* const* d_in, const int* in_sizes, int n_in,
                              void* d_out, int out_size, void* d_ws, size_t ws_size,
                              hipStream_t stream)
{
  const float* x_sh  = (const float*)d_in[0];
  const float* x_t1  = (const float*)d_in[1];
  const float* x_t2  = (const float*)d_in[2];
  const float* w1_sh = (const float*)d_in[3];
  const float* b1_sh = (const float*)d_in[4];
  const float* w2_sh = (const float*)d_in[5];
  const float* b2_sh = (const float*)d_in[6];
  const float* w1_t1 = (const float*)d_in[7];
  const float* b1_t1 = (const float*)d_in[8];
  const float* w2_t1 = (const float*)d_in[9];
  const float* b2_t1 = (const float*)d_in[10];
  const float* w1_t2 = (const float*)d_in[11];
  const float* b1_t2 = (const float*)d_in[12];
  const float* w2_t2 = (const float*)d_in[13];
  const float* b2_t2 = (const float*)d_in[14];
  const float* wg_sh = (const float*)d_in[15];
  const float* bg_sh = (const float*)d_in[16];
  const float* wg_t1 = (const float*)d_in[17];
  const float* bg_t1 = (const float*)d_in[18];
  const float* wg_t2 = (const float*)d_in[19];
  const float* bg_t2 = (const float*)d_in[20];

  char* p = (char*)d_ws;
  auto alloc = [&](size_t bytes) { char* r = p; p += (bytes + 255) & ~(size_t)255; return r; };

  ushort_t* xb    = (ushort_t*)alloc(3ull * B_DIM * I_DIM * 2);    // 25.2 MB
  ushort_t* eout  = (ushort_t*)alloc(12ull * B_DIM * O_DIM * 2);   // 50.3 MB
  float*    gates = (float*)alloc(28ull * B_DIM * 4);              // 0.46 MB
  ushort_t* wgtb  = (ushort_t*)alloc(3ull * 16 * I_DIM * 2);       // 96 KB

  const size_t used_fixed = (size_t)(p - (char*)d_ws);
  const size_t per_e = ((size_t)H_DIM * I_DIM + (size_t)O_DIM * H_DIM + (size_t)B_DIM * H_DIM) * 2 + 3 * 256;
  int eb = 1;
  if (ws_size > used_fixed + per_e) eb = (int)((ws_size - used_fixed) / per_e);
  if (eb > 12) eb = 12;
  if (eb < 1)  eb = 1;

  ushort_t* w1t  = (ushort_t*)alloc((size_t)eb * H_DIM * I_DIM * 2);
  ushort_t* w2t  = (ushort_t*)alloc((size_t)eb * O_DIM * H_DIM * 2);
  ushort_t* hbuf = (ushort_t*)alloc((size_t)eb * B_DIM * H_DIM * 2);

  cast_x_kernel<<<dim3(2048, 3), 256, 0, stream>>>(x_t1, x_t2, x_sh, xb);
  prep_gates_w_kernel<<<3, 256, 0, stream>>>(wg_sh, wg_t1, wg_t2, wgtb);
  gates_direct_kernel<<<dim3(B_DIM / 64, 3), 256, 0, stream>>>(xb, wgtb, bg_sh, bg_t1, bg_t2, gates);
  for (int ebase = 0; ebase < 12; ebase += eb) {
    const int cnt = (12 - ebase < eb) ? (12 - ebase) : eb;
    tcast64_kernel<<<dim3(H_DIM / 32, I_DIM / 64, cnt), dim3(32, 8), 0, stream>>>(
        w1_t1, w1_t2, w1_sh, w1t, I_DIM, H_DIM, ebase);
    tcast64_kernel<<<dim3(O_DIM / 32, H_DIM / 64, cnt), dim3(32, 8), 0, stream>>>(
        w2_t1, w2_t2, w2_sh, w2t, H_DIM, O_DIM, ebase);
    gemm1_256_kernel<<<dim3(H_DIM / 256, B_DIM / 256, cnt), 512, 0, stream>>>(
        xb, w1t, b1_t1, b1_t2, b1_sh, hbuf, ebase);
    gemm2_128_kernel<<<dim3(O_DIM / 128, B_DIM / 128, cnt), 256, 0, stream>>>(
        hbuf, w2t, b2_t1, b2_t2, b2_sh, eout, ebase);
  }
  combine_kernel<<<dim3((B_DIM * O_DIM / 8) / 256), 256, 0, stream>>>(eout, gates, (float*)d_out);
}

// Round 13
// 398.276 us; speedup vs baseline: 1.1756x; 1.1756x over previous
//
#include <hip/hip_runtime.h>

#define B_DIM 4096
#define I_DIM 1024
#define H_DIM 2048
#define O_DIM 512

typedef unsigned short ushort_t;
typedef unsigned long long ull_t;
typedef __attribute__((ext_vector_type(4))) float f32x4;
typedef __attribute__((ext_vector_type(8))) short bf16x8;     // 8 bf16 bit-patterns (4 VGPRs)
typedef __attribute__((ext_vector_type(8))) unsigned short u16x8;
typedef __attribute__((ext_vector_type(4))) unsigned short u16x4;

// ---- bf16 helpers (RNE) ----
__device__ __forceinline__ unsigned short f2bf(float f) {
  union { float f; unsigned int u; } v; v.f = f;
  unsigned int u = v.u;
  u += 0x7fffu + ((u >> 16) & 1u);
  return (unsigned short)(u >> 16);
}
__device__ __forceinline__ float bf2f(unsigned short h) {
  union { unsigned int u; float f; } v; v.u = ((unsigned int)h) << 16;
  return v.f;
}

// ---- async global->LDS, 16B per lane. LDS dest must be wave-uniform base + lane*16. ----
__device__ __forceinline__ void gld16(const void* g, void* l) {
  __builtin_amdgcn_global_load_lds(
      (const __attribute__((address_space(1))) unsigned int*)((ull_t)g),
      (__attribute__((address_space(3))) unsigned int*)((unsigned int)(ull_t)l),
      16, 0, 0);
}

// st_16x32 swizzle within a [rows][64] bf16 tile stored as [16-row][32-col] subtiles:
// byte off ^= ((off>>9)&1)<<5 inside each 1024B subtile (involution).
__device__ __forceinline__ int swz_off(int row, int col) {
  int off = ((((row >> 4) << 1) + (col >> 5)) << 10) + ((row & 15) << 6) + ((col & 31) << 1);
  off ^= ((row >> 3) & 1) << 5;
  return off;
}

// =====================================================================
// Parameterized tile GEMM: BM=WM*MR*16, BN=WN*NR*16, BK=64, WM*WN waves,
// double-buffered swizzled LDS, 4-phase quadrant schedule, counted vmcnt,
// R7/R10-measured-best barriers (3/K-tile): entry, post-p1 (frees B region
// -> stageB at p2), post-p2 (frees A region -> stageA at p3).
// Direct global-store epilogue. This schedule is a measured local optimum:
// R5 (9-barrier), R8 (2-barrier), R11 (128^2 tile), R12 (read-hoisting)
// all measured worse or neutral.
// C[M,N] = act(A[M,K] @ Bt[N,K]^T + bias)
// =====================================================================
template <bool RELU, int WM, int WN, int MR, int NR>
__device__ __forceinline__ void gemm_core(
    const ushort_t* __restrict__ A,    // [M][K] bf16 bits, row-major
    const ushort_t* __restrict__ Bt,   // [N][K] bf16 bits, row-major
    const float*    __restrict__ bias, // [N]
    ushort_t*       __restrict__ C,    // [M][N] bf16 bits
    int N, int K, int bm0, int bn0)
{
  constexpr int BM = WM * MR * 16;
  constexpr int BN = WN * NR * 16;
  constexpr int NTH = WM * WN * 64;
  constexpr int MH = MR / 2, NH = NR / 2;
  constexpr int ABYTES = BM * 128;     // BM x 64 x 2B
  constexpr int BBYTES = BN * 128;
  constexpr int CA = ABYTES / (NTH * 16);   // 16B staging chunks / thread / K-tile
  constexpr int CB = BBYTES / (NTH * 16);
  constexpr int VM = CA + CB;          // per-thread loads per K-tile

  __shared__ __align__(16) char lds[2 * (ABYTES + BBYTES)];

  const int tid  = threadIdx.x;
  const int lane = tid & 63;
  const int wave = tid >> 6;
  const int wm = wave / WN, wn = wave % WN;
  const int r16 = lane & 15, kq = lane >> 4;

  // ---- staging maps: linear LDS dest + inverse-swizzled global source ----
  int loffA[CA]; ull_t goffA[CA];
  int loffB[CB]; ull_t goffB[CB];
#pragma unroll
  for (int r = 0; r < CA; ++r) {
    const int L = (r * NTH + tid) * 16;
    const int P = L ^ (((L >> 9) & 1) << 5);
    const int s = P >> 10;
    const int row = ((s >> 1) << 4) | ((P >> 6) & 15);
    const int col = ((s & 1) << 5) | (((P >> 4) & 3) << 3);
    loffA[r] = L;
    goffA[r] = (ull_t)(bm0 + row) * K + col;
  }
#pragma unroll
  for (int r = 0; r < CB; ++r) {
    const int L = (r * NTH + tid) * 16;
    const int P = L ^ (((L >> 9) & 1) << 5);
    const int s = P >> 10;
    const int row = ((s >> 1) << 4) | ((P >> 6) & 15);
    const int col = ((s & 1) << 5) | (((P >> 4) & 3) << 3);
    loffB[r] = L;
    goffB[r] = (ull_t)(bn0 + row) * K + col;
  }
  const int NT = K >> 6;

  // ---- swizzled read offsets, constant across K-tiles ----
  int offA[MR][2], offB[NR][2];
#pragma unroll
  for (int m = 0; m < MR; ++m)
#pragma unroll
    for (int ks = 0; ks < 2; ++ks)
      offA[m][ks] = swz_off(wm * MR * 16 + m * 16 + r16, ks * 32 + kq * 8);
#pragma unroll
  for (int n = 0; n < NR; ++n)
#pragma unroll
    for (int ks = 0; ks < 2; ++ks)
      offB[n][ks] = swz_off(wn * NR * 16 + n * 16 + r16, ks * 32 + kq * 8);

  f32x4 acc[MR][NR] = {};

  auto stageA = [&](int b, int kt) {
    char* base = lds + b * (ABYTES + BBYTES);
    const int k0 = kt << 6;
#pragma unroll
    for (int r = 0; r < CA; ++r) gld16(A + goffA[r] + k0, base + loffA[r]);
  };
  auto stageB = [&](int b, int kt) {
    char* base = lds + b * (ABYTES + BBYTES) + ABYTES;
    const int k0 = kt << 6;
#pragma unroll
    for (int r = 0; r < CB; ++r) gld16(Bt + goffB[r] + k0, base + loffB[r]);
  };

  stageA(0, 0); stageB(0, 0);
  stageA(1, 1); stageB(1, 1);   // NT >= 2 always here

  for (int kt = 0; kt < NT; ++kt) {
    const int b = kt & 1;
    const bool pre = (kt + 2 < NT);
    if (kt < NT - 1) {
      if constexpr (VM == 8)      asm volatile("s_waitcnt vmcnt(8)" ::: "memory");
      else if constexpr (VM == 4) asm volatile("s_waitcnt vmcnt(4)" ::: "memory");
      else                        asm volatile("s_waitcnt vmcnt(0)" ::: "memory");
    } else {
      asm volatile("s_waitcnt vmcnt(0)" ::: "memory");
    }
    __builtin_amdgcn_s_barrier();   // entry: all waves' kt loads landed & visible

    const char* tA = lds + b * (ABYTES + BBYTES);
    const char* tB = tA + ABYTES;

    bf16x8 a_lo[MH][2], a_hi[MH][2], b_lo[NH][2], b_hi[NH][2];

    // ---- p0: reads a_lo + b_lo, MFMA q(0,0) — no barrier ----
#pragma unroll
    for (int m = 0; m < MH; ++m) {
      a_lo[m][0] = *(const bf16x8*)(tA + offA[m][0]);
      a_lo[m][1] = *(const bf16x8*)(tA + offA[m][1]);
    }
#pragma unroll
    for (int n = 0; n < NH; ++n) {
      b_lo[n][0] = *(const bf16x8*)(tB + offB[n][0]);
      b_lo[n][1] = *(const bf16x8*)(tB + offB[n][1]);
    }
    asm volatile("s_waitcnt lgkmcnt(0)" ::: "memory");
    __builtin_amdgcn_sched_barrier(0);
    __builtin_amdgcn_s_setprio(1);
#pragma unroll
    for (int m = 0; m < MH; ++m)
#pragma unroll
      for (int n = 0; n < NH; ++n)
#pragma unroll
        for (int ks = 0; ks < 2; ++ks)
          acc[m][n] = __builtin_amdgcn_mfma_f32_16x16x32_bf16(a_lo[m][ks], b_lo[n][ks], acc[m][n], 0, 0, 0);
    __builtin_amdgcn_s_setprio(0);

    // ---- p1: reads b_hi, MFMA q(0,1) ----
#pragma unroll
    for (int n = 0; n < NH; ++n) {
      b_hi[n][0] = *(const bf16x8*)(tB + offB[n + NH][0]);
      b_hi[n][1] = *(const bf16x8*)(tB + offB[n + NH][1]);
    }
    asm volatile("s_waitcnt lgkmcnt(0)" ::: "memory");
    __builtin_amdgcn_sched_barrier(0);
    __builtin_amdgcn_s_setprio(1);
#pragma unroll
    for (int m = 0; m < MH; ++m)
#pragma unroll
      for (int n = 0; n < NH; ++n)
#pragma unroll
        for (int ks = 0; ks < 2; ++ks)
          acc[m][n + NH] = __builtin_amdgcn_mfma_f32_16x16x32_bf16(a_lo[m][ks], b_hi[n][ks], acc[m][n + NH], 0, 0, 0);
    __builtin_amdgcn_s_setprio(0);
    asm volatile("" ::: "memory");
    __builtin_amdgcn_s_barrier();   // all waves drained all B reads of buf b

    // ---- p2: reads a_hi, stage B(kt+2) into freed B region, MFMA q(1,1) ----
#pragma unroll
    for (int m = 0; m < MH; ++m) {
      a_hi[m][0] = *(const bf16x8*)(tA + offA[m + MH][0]);
      a_hi[m][1] = *(const bf16x8*)(tA + offA[m + MH][1]);
    }
    if (pre) stageB(b, kt + 2);
    asm volatile("s_waitcnt lgkmcnt(0)" ::: "memory");
    __builtin_amdgcn_sched_barrier(0);
    __builtin_amdgcn_s_setprio(1);
#pragma unroll
    for (int m = 0; m < MH; ++m)
#pragma unroll
      for (int n = 0; n < NH; ++n)
#pragma unroll
        for (int ks = 0; ks < 2; ++ks)
          acc[m + MH][n + NH] = __builtin_amdgcn_mfma_f32_16x16x32_bf16(a_hi[m][ks], b_hi[n][ks], acc[m + MH][n + NH], 0, 0, 0);
    __builtin_amdgcn_s_setprio(0);
    asm volatile("" ::: "memory");
    __builtin_amdgcn_s_barrier();   // all waves drained all A reads of buf b

    // ---- p3: stage A(kt+2) into freed A region, MFMA q(1,0) (regs only) ----
    if (pre) stageA(b, kt + 2);
    __builtin_amdgcn_sched_barrier(0);
    __builtin_amdgcn_s_setprio(1);
#pragma unroll
    for (int m = 0; m < MH; ++m)
#pragma unroll
      for (int n = 0; n < NH; ++n)
#pragma unroll
        for (int ks = 0; ks < 2; ++ks)
          acc[m + MH][n] = __builtin_amdgcn_mfma_f32_16x16x32_bf16(a_hi[m][ks], b_lo[n][ks], acc[m + MH][n], 0, 0, 0);
    __builtin_amdgcn_s_setprio(0);
  }

  // ---- epilogue: direct global stores (measured best) ----
  float bv[NR];
#pragma unroll
  for (int n = 0; n < NR; ++n) bv[n] = bias[bn0 + wn * NR * 16 + n * 16 + r16];
#pragma unroll
  for (int m = 0; m < MR; ++m) {
    const int row = bm0 + wm * MR * 16 + m * 16 + kq * 4;
#pragma unroll
    for (int n = 0; n < NR; ++n) {
      const int col = bn0 + wn * NR * 16 + n * 16 + r16;
#pragma unroll
      for (int j = 0; j < 4; ++j) {
        float v = acc[m][n][j] + bv[n];
        if (RELU) v = fmaxf(v, 0.f);
        C[(ull_t)(row + j) * N + col] = f2bf(v);
      }
    }
  }
}

// bijective XCD swizzle of the flattened grid (total % 8 == 0 for all our grids)
__device__ __forceinline__ void xcd_swz(int& bx, int& by, int& bz) {
  const int gx = gridDim.x, gy = gridDim.y;
  const int total = gx * gy * gridDim.z;
  const int flat = blockIdx.x + gx * (blockIdx.y + gy * blockIdx.z);
  const int q = total >> 3;
  const int s = (flat & 7) * q + (flat >> 3);
  bx = s % gx;
  const int rest = s / gx;
  by = rest % gy;
  bz = rest / gy;
}

// expert order: 0-3 = task1, 4-7 = task2, 8-11 = shared
__global__ __launch_bounds__(512, 2) void gemm1_256_kernel(
    const ushort_t* __restrict__ xb,   // [3][B][I] bf16 (slot 0=t1,1=t2,2=sh)
    const ushort_t* __restrict__ w1t,  // [cnt][H][I] bf16
    const float* __restrict__ b1_t1, const float* __restrict__ b1_t2, const float* __restrict__ b1_sh,
    ushort_t* __restrict__ hbuf,       // [cnt][B][H] bf16
    int ebase)
{
  int bx, by, bz; xcd_swz(bx, by, bz);
  const int eg = ebase + bz;
  const ushort_t* A  = xb + (ull_t)(eg >> 2) * B_DIM * I_DIM;
  const ushort_t* Bt = w1t + (ull_t)bz * H_DIM * I_DIM;
  const float* bias = (eg < 4 ? b1_t1 : eg < 8 ? b1_t2 : b1_sh) + (ull_t)(eg & 3) * H_DIM;
  ushort_t* C = hbuf + (ull_t)bz * B_DIM * H_DIM;
  gemm_core<true, 2, 4, 8, 4>(A, Bt, bias, C, H_DIM, I_DIM, by * 256, bx * 256);
}

// gemm2: 128x128 tile, 4 waves, 64KB LDS -> 2 blocks/CU; grid 4x32x12 = 1536 = 3 rounds
__global__ __launch_bounds__(256, 2) void gemm2_128_kernel(
    const ushort_t* __restrict__ hbuf, // [cnt][B][H] bf16
    const ushort_t* __restrict__ w2t,  // [cnt][O][H] bf16
    const float* __restrict__ b2_t1, const float* __restrict__ b2_t2, const float* __restrict__ b2_sh,
    ushort_t* __restrict__ eout,       // [12][B][O] bf16
    int ebase)
{
  int bx, by, bz; xcd_swz(bx, by, bz);
  const int eg = ebase + bz;
  const ushort_t* A  = hbuf + (ull_t)bz * B_DIM * H_DIM;
  const ushort_t* Bt = w2t + (ull_t)bz * O_DIM * H_DIM;
  const float* bias = (eg < 4 ? b2_t1 : eg < 8 ? b2_t2 : b2_sh) + (ull_t)(eg & 3) * O_DIM;
  ushort_t* C = eout + (ull_t)eg * B_DIM * O_DIM;
  gemm_core<false, 2, 2, 4, 4>(A, Bt, bias, C, O_DIM, H_DIM, by * 128, bx * 128);
}

// transpose-cast fp32 [R][C] -> bf16 [C][R]; 64x32 tiles, u16x8 (16B) writes
__global__ void tcast64_kernel(const float* __restrict__ s_t1, const float* __restrict__ s_t2,
                               const float* __restrict__ s_sh, ushort_t* __restrict__ dst,
                               int R, int C, int ebase)
{
  __shared__ float tile[64][33];
  const int eg = ebase + blockIdx.z;
  const float* src = (eg < 4 ? s_t1 : eg < 8 ? s_t2 : s_sh) + (ull_t)(eg & 3) * R * C;
  ushort_t* d = dst + (ull_t)blockIdx.z * R * C;
  const int tx = threadIdx.x, ty = threadIdx.y;   // 32 x 8
  const int r0 = blockIdx.y * 64, c0 = blockIdx.x * 32;
#pragma unroll
  for (int i = 0; i < 64; i += 8)
    tile[i + ty][tx] = src[(ull_t)(r0 + i + ty) * C + c0 + tx];
  __syncthreads();
  const int tid = ty * 32 + tx;
  const int c = tid >> 3, q = tid & 7;
  u16x8 rv;
#pragma unroll
  for (int k = 0; k < 8; ++k) rv[k] = f2bf(tile[q * 8 + k][c]);
  *(u16x8*)(d + (ull_t)(c0 + c) * R + r0 + q * 8) = rv;
}

// cast x fp32 -> bf16, 8 elems/thread
__global__ void cast_x_kernel(const float* __restrict__ xt1, const float* __restrict__ xt2,
                              const float* __restrict__ xsh, ushort_t* __restrict__ dst)
{
  const int slot = blockIdx.y;
  const float* src = slot == 0 ? xt1 : slot == 1 ? xt2 : xsh;
  const ull_t base = ((ull_t)blockIdx.x * 256 + threadIdx.x) * 8;
  const f32x4* s4 = (const f32x4*)(src + base);
  f32x4 a = s4[0], b = s4[1];
  u16x8 r;
  r[0] = f2bf(a[0]); r[1] = f2bf(a[1]); r[2] = f2bf(a[2]); r[3] = f2bf(a[3]);
  r[4] = f2bf(b[0]); r[5] = f2bf(b[1]); r[6] = f2bf(b[2]); r[7] = f2bf(b[3]);
  *(u16x8*)(dst + (ull_t)slot * B_DIM * I_DIM + base) = r;
}

// prep: transpose-cast gate weights [1024][n] fp32 -> [16][1024] bf16 (zero-padded cols)
__global__ void prep_gates_w_kernel(const float* __restrict__ wg_sh, const float* __restrict__ wg_t1,
                                    const float* __restrict__ wg_t2, ushort_t* __restrict__ wgtb)
{
  const int t = blockIdx.x;
  const float* src = t == 0 ? wg_sh : t == 1 ? wg_t1 : wg_t2;
  const int n = t == 0 ? 12 : 8;
  ushort_t* dst = wgtb + (ull_t)t * 16 * I_DIM;
  for (int i = threadIdx.x; i < 16 * (I_DIM / 8); i += blockDim.x) {
    const int c = i >> 7, j0 = (i & 127) * 8;
    u16x8 r;
#pragma unroll
    for (int k = 0; k < 8; ++k)
      r[k] = (c < n) ? f2bf(src[(ull_t)(j0 + k) * n + c]) : (ushort_t)0;
    *(u16x8*)(dst + (ull_t)c * I_DIM + j0) = r;
  }
}

// gates, LDS-free: each wave computes 16 rows x 16 gate-cols via direct-read
// MFMA (dual acc chains for ILP), then 16-lane-group softmax.
__global__ __launch_bounds__(256) void gates_direct_kernel(
    const ushort_t* __restrict__ xb, const ushort_t* __restrict__ wgtb,
    const float* __restrict__ bg_sh, const float* __restrict__ bg_t1, const float* __restrict__ bg_t2,
    float* __restrict__ gates)  // gs[B][12] | g1[B][8] | g2[B][8]
{
  const int task = blockIdx.y;
  const int slot = task == 0 ? 2 : task - 1;
  const int n = task == 0 ? 12 : 8;
  const float* bg = task == 0 ? bg_sh : task == 1 ? bg_t1 : bg_t2;
  float* out = task == 0 ? gates
             : task == 1 ? gates + (ull_t)B_DIM * 12
                         : gates + (ull_t)B_DIM * 20;

  const int lane = threadIdx.x & 63, wave = threadIdx.x >> 6;
  const int r16 = lane & 15, kq = lane >> 4;
  const int brow = blockIdx.x * 64 + wave * 16;

  const ushort_t* Arow = xb + (ull_t)slot * B_DIM * I_DIM + (ull_t)(brow + r16) * I_DIM + kq * 8;
  const ushort_t* Brow = wgtb + (ull_t)task * 16 * I_DIM + (ull_t)r16 * I_DIM + kq * 8;

  f32x4 acc0 = {}, acc1 = {};
#pragma unroll
  for (int k0 = 0; k0 < I_DIM; k0 += 64) {
    const bf16x8 a0 = *(const bf16x8*)(Arow + k0);
    const bf16x8 b0 = *(const bf16x8*)(Brow + k0);
    const bf16x8 a1 = *(const bf16x8*)(Arow + k0 + 32);
    const bf16x8 b1 = *(const bf16x8*)(Brow + k0 + 32);
    acc0 = __builtin_amdgcn_mfma_f32_16x16x32_bf16(a0, b0, acc0, 0, 0, 0);
    acc1 = __builtin_amdgcn_mfma_f32_16x16x32_bf16(a1, b1, acc1, 0, 0, 0);
  }

  const float bv = (r16 < n) ? bg[r16] : 0.f;
#pragma unroll
  for (int j = 0; j < 4; ++j) {
    float v = (r16 < n) ? (acc0[j] + acc1[j] + bv) : -1e30f;
    float mx = v;
#pragma unroll
    for (int d = 1; d < 16; d <<= 1) mx = fmaxf(mx, __shfl_xor(mx, d));
    const float e = __expf(v - mx);
    float s = e;
#pragma unroll
    for (int d = 1; d < 16; d <<= 1) s += __shfl_xor(s, d);
    const int row = brow + kq * 4 + j;
    if (r16 < n) out[(ull_t)row * n + r16] = e / s;
  }
}

// combine: out_sh = sum_j gs[j]*E[j]; out1 = g1 over {t1,sh}; out2 = g2 over {t2,sh}
__global__ __launch_bounds__(256) void combine_kernel(
    const ushort_t* __restrict__ eout, const float* __restrict__ gates, float* __restrict__ out)
{
  const ull_t idx8 = (ull_t)blockIdx.x * 256 + threadIdx.x;  // over B*O/8
  const int b  = (int)(idx8 >> 6);          // O/8 = 64 groups per row
  const int o8 = ((int)idx8 & 63) * 8;
  const float* gs = gates + (ull_t)b * 12;
  const float* g1 = gates + (ull_t)B_DIM * 12 + (ull_t)b * 8;
  const float* g2 = gates + (ull_t)B_DIM * 20 + (ull_t)b * 8;
  float osh[8] = {}, o1[8] = {}, o2[8] = {};
#pragma unroll
  for (int j = 0; j < 12; ++j) {
    const u16x8 ev = *(const u16x8*)(eout + ((ull_t)j * B_DIM + b) * O_DIM + o8);
    const float wsh = gs[j];
    const float w1 = (j < 4) ? g1[j] : (j >= 8 ? g1[j - 4] : 0.f);
    const float w2 = (j < 4) ? 0.f : g2[j - 4];
#pragma unroll
    for (int t = 0; t < 8; ++t) {
      const float e = bf2f(ev[t]);
      osh[t] += wsh * e; o1[t] += w1 * e; o2[t] += w2 * e;
    }
  }
  const ull_t nBO = (ull_t)B_DIM * O_DIM;
  const ull_t obase = (ull_t)b * O_DIM + o8;
#pragma unroll
  for (int h = 0; h < 2; ++h) {
    f32x4 v0 = {osh[h*4], osh[h*4+1], osh[h*4+2], osh[h*4+3]};
    f32x4 v1 = {o1[h*4], o1[h*4+1], o1[h*4+2], o1[h*4+3]};
    f32x4 v2 = {o2[h*4], o2[h*4+1], o2[h*4+2], o2[h*4+3]};
    *(f32x4*)(out + obase + h*4) = v0;
    *(f32x4*)(out + nBO + obase + h*4) = v1;
    *(f32x4*)(out + 2 * nBO + obase + h*4) = v2;
  }
}

extern "C" void kernel_launch(void* const* d_in, const int* in_sizes, int n_in,
                              void* d_out, int out_size, void* d_ws, size_t ws_size,
                              hipStream_t stream)
{
  const float* x_sh  = (const float*)d_in[0];
  const float* x_t1  = (const float*)d_in[1];
  const float* x_t2  = (const float*)d_in[2];
  const float* w1_sh = (const float*)d_in[3];
  const float* b1_sh = (const float*)d_in[4];
  const float* w2_sh = (const float*)d_in[5];
  const float* b2_sh = (const float*)d_in[6];
  const float* w1_t1 = (const float*)d_in[7];
  const float* b1_t1 = (const float*)d_in[8];
  const float* w2_t1 = (const float*)d_in[9];
  const float* b2_t1 = (const float*)d_in[10];
  const float* w1_t2 = (const float*)d_in[11];
  const float* b1_t2 = (const float*)d_in[12];
  const float* w2_t2 = (const float*)d_in[13];
  const float* b2_t2 = (const float*)d_in[14];
  const float* wg_sh = (const float*)d_in[15];
  const float* bg_sh = (const float*)d_in[16];
  const float* wg_t1 = (const float*)d_in[17];
  const float* bg_t1 = (const float*)d_in[18];
  const float* wg_t2 = (const float*)d_in[19];
  const float* bg_t2 = (const float*)d_in[20];

  char* p = (char*)d_ws;
  auto alloc = [&](size_t bytes) { char* r = p; p += (bytes + 255) & ~(size_t)255; return r; };

  ushort_t* xb    = (ushort_t*)alloc(3ull * B_DIM * I_DIM * 2);    // 25.2 MB
  ushort_t* eout  = (ushort_t*)alloc(12ull * B_DIM * O_DIM * 2);   // 50.3 MB
  float*    gates = (float*)alloc(28ull * B_DIM * 4);              // 0.46 MB
  ushort_t* wgtb  = (ushort_t*)alloc(3ull * 16 * I_DIM * 2);       // 96 KB

  const size_t used_fixed = (size_t)(p - (char*)d_ws);
  const size_t per_e = ((size_t)H_DIM * I_DIM + (size_t)O_DIM * H_DIM + (size_t)B_DIM * H_DIM) * 2 + 3 * 256;
  int eb = 1;
  if (ws_size > used_fixed + per_e) eb = (int)((ws_size - used_fixed) / per_e);
  if (eb > 12) eb = 12;
  if (eb < 1)  eb = 1;

  ushort_t* w1t  = (ushort_t*)alloc((size_t)eb * H_DIM * I_DIM * 2);
  ushort_t* w2t  = (ushort_t*)alloc((size_t)eb * O_DIM * H_DIM * 2);
  ushort_t* hbuf = (ushort_t*)alloc((size_t)eb * B_DIM * H_DIM * 2);

  cast_x_kernel<<<dim3(2048, 3), 256, 0, stream>>>(x_t1, x_t2, x_sh, xb);
  prep_gates_w_kernel<<<3, 256, 0, stream>>>(wg_sh, wg_t1, wg_t2, wgtb);
  gates_direct_kernel<<<dim3(B_DIM / 64, 3), 256, 0, stream>>>(xb, wgtb, bg_sh, bg_t1, bg_t2, gates);
  for (int ebase = 0; ebase < 12; ebase += eb) {
    const int cnt = (12 - ebase < eb) ? (12 - ebase) : eb;
    tcast64_kernel<<<dim3(H_DIM / 32, I_DIM / 64, cnt), dim3(32, 8), 0, stream>>>(
        w1_t1, w1_t2, w1_sh, w1t, I_DIM, H_DIM, ebase);
    tcast64_kernel<<<dim3(O_DIM / 32, H_DIM / 64, cnt), dim3(32, 8), 0, stream>>>(
        w2_t1, w2_t2, w2_sh, w2t, H_DIM, O_DIM, ebase);
    gemm1_256_kernel<<<dim3(H_DIM / 256, B_DIM / 256, cnt), 512, 0, stream>>>(
        xb, w1t, b1_t1, b1_t2, b1_sh, hbuf, ebase);
    gemm2_128_kernel<<<dim3(O_DIM / 128, B_DIM / 128, cnt), 256, 0, stream>>>(
        hbuf, w2t, b2_t1, b2_t2, b2_sh, eout, ebase);
  }
  combine_kernel<<<dim3((B_DIM * O_DIM / 8) / 256), 256, 0, stream>>>(eout, gates, (float*)d_out);
}